// Round 2
// baseline (384.036 us; speedup 1.0000x reference)
//
#include <hip/hip_runtime.h>

// FlowGuidedDCN: deformable 3x3 conv, stride=1, pad=1, dilation=1
// x: [B=8, C=3, H=512, W=512] f32
// offsets: [B, 18, H, W] f32  (dy,dx interleaved per tap: ch 2k=dy, 2k+1=dx)
// weight: [O=16, C=3, 3, 3] f32 ; bias: [16] f32
// out: [B, 16, H, W] f32

#define Bc 8
#define Cc 3
#define Hc 512
#define Wc 512
#define Oc 16
#define HWc (512 * 512)
#define KKc 9

__global__ __launch_bounds__(256) void dcn_kernel(
    const float* __restrict__ x,
    const float* __restrict__ offsets,
    const float* __restrict__ weight,
    const float* __restrict__ bias,
    float* __restrict__ out) {
  int pix = blockIdx.x * 256 + threadIdx.x;   // 0 .. B*H*W-1
  int b = pix >> 18;                          // / (512*512)
  int hw = pix & (HWc - 1);
  int h = hw >> 9;
  int w = hw & 511;

  const float* xb = x + b * (Cc * HWc);
  const float* ob = offsets + b * (2 * KKc * HWc) + hw;

  float acc[Oc];
#pragma unroll
  for (int o = 0; o < Oc; ++o) acc[o] = bias[o];

  const float fh = (float)(h - 1);  // h - PAD
  const float fw = (float)(w - 1);

#pragma unroll
  for (int kk = 0; kk < KKc; ++kk) {
    const int ky = kk / 3;
    const int kx = kk % 3;
    float oy = ob[(2 * kk) * HWc];
    float ox = ob[(2 * kk + 1) * HWc];
    float py = oy + fh + (float)ky;
    float px = ox + fw + (float)kx;
    float y0f = floorf(py);
    float x0f = floorf(px);
    float wy = py - y0f;
    float wx = px - x0f;
    int y0 = (int)y0f;
    int x0 = (int)x0f;
    int y1 = y0 + 1;
    int x1 = x0 + 1;

    // validity folded into bilinear weights (factors are exactly 0.0/1.0,
    // bit-exact vs reference's v*valid since invalid corners multiply by 0)
    float vy0 = ((unsigned)y0 < (unsigned)Hc) ? 1.f : 0.f;
    float vy1 = ((unsigned)y1 < (unsigned)Hc) ? 1.f : 0.f;
    float vx0 = ((unsigned)x0 < (unsigned)Wc) ? 1.f : 0.f;
    float vx1 = ((unsigned)x1 < (unsigned)Wc) ? 1.f : 0.f;
    float wy0 = 1.f - wy;
    float wx0 = 1.f - wx;
    float w00 = (wy0 * wx0) * (vy0 * vx0);
    float w01 = (wy0 * wx) * (vy0 * vx1);
    float w10 = (wy * wx0) * (vy1 * vx0);
    float w11 = (wy * wx) * (vy1 * vx1);

    int y0c = min(max(y0, 0), Hc - 1);
    int y1c = min(max(y1, 0), Hc - 1);
    int x0c = min(max(x0, 0), Wc - 1);
    int x1c = min(max(x1, 0), Wc - 1);
    int a00 = (y0c << 9) + x0c;
    int a01 = (y0c << 9) + x1c;
    int a10 = (y1c << 9) + x0c;
    int a11 = (y1c << 9) + x1c;

    float val[Cc];
#pragma unroll
    for (int c = 0; c < Cc; ++c) {
      const float* xc = xb + c * HWc;
      float v00 = xc[a00];
      float v01 = xc[a01];
      float v10 = xc[a10];
      float v11 = xc[a11];
      val[c] = v00 * w00 + v01 * w01 + v10 * w10 + v11 * w11;
    }

    // einsum tap contribution: acc[o] += w[o][c][kk] * val[c]
    // compile-time weight indices -> uniform s_load from K$, SGPR feeds v_fmac
    const float* wk = weight + kk;
#pragma unroll
    for (int o = 0; o < Oc; ++o) {
#pragma unroll
      for (int c = 0; c < Cc; ++c) {
        acc[o] = fmaf(wk[o * (Cc * KKc) + c * KKc], val[c], acc[o]);
      }
    }
  }

  float* op = out + b * (Oc * HWc) + hw;
#pragma unroll
  for (int o = 0; o < Oc; ++o) op[o * HWc] = acc[o];
}

extern "C" void kernel_launch(void* const* d_in, const int* in_sizes, int n_in,
                              void* d_out, int out_size, void* d_ws, size_t ws_size,
                              hipStream_t stream) {
  const float* x = (const float*)d_in[0];
  const float* offsets = (const float*)d_in[1];
  const float* weight = (const float*)d_in[2];
  const float* bias = (const float*)d_in[3];
  float* out = (float*)d_out;

  const int total = Bc * HWc;  // 2,097,152 threads
  dim3 grid(total / 256);
  dim3 block(256);
  hipLaunchKernelGGL(dcn_kernel, grid, block, 0, stream, x, offsets, weight, bias, out);
}

// Round 3
// 369.153 us; speedup vs baseline: 1.0403x; 1.0403x over previous
//
#include <hip/hip_runtime.h>

// FlowGuidedDCN: deformable 3x3 conv, stride=1, pad=1, dilation=1
// x: [B=8, C=3, H=512, W=512] f32
// offsets: [B, 18, H, W] f32  (ch 2k=dy, 2k+1=dx per tap)
// weight: [O=16, C=3, 3, 3] f32 ; bias: [16] f32
// out: [B, 16, H, W] f32

#define Bc 8
#define Cc 3
#define Hc 512
#define Wc 512
#define Oc 16
#define HWc (512 * 512)
#define KKc 9

// ---------- pass 1: x[B,C,H,W] -> xt[B,H,W,4] (channel-last, lane3 = 0) ----------
__global__ __launch_bounds__(256) void transpose_kernel(
    const float* __restrict__ x, float4* __restrict__ xt) {
  int pix = blockIdx.x * 256 + threadIdx.x;  // 0 .. B*H*W-1
  int b = pix >> 18;
  int hw = pix & (HWc - 1);
  const float* xb = x + b * (Cc * HWc) + hw;
  float4 v;
  v.x = xb[0];
  v.y = xb[HWc];
  v.z = xb[2 * HWc];
  v.w = 0.f;
  xt[pix] = v;  // fully coalesced 16B store
}

// ---------- pass 2: main DCN, channels-last gathers ----------
__global__ __launch_bounds__(256, 4) void dcn_main(
    const float4* __restrict__ xt,
    const float* __restrict__ offsets,
    const float* __restrict__ weight,
    const float* __restrict__ bias,
    float* __restrict__ out) {
  int pix = blockIdx.x * 256 + threadIdx.x;
  int b = pix >> 18;
  int hw = pix & (HWc - 1);
  int h = hw >> 9;
  int w = hw & 511;

  const float4* xb = xt + (b << 18);
  const float* ob = offsets + b * (2 * KKc * HWc) + hw;

  const float fh = (float)(h - 1);  // h - PAD
  const float fw = (float)(w - 1);

  // phase 1: all addresses + bilinear weights (no dependence on gathers)
  int addr[KKc][4];
  float wt[KKc][4];
#pragma unroll
  for (int kk = 0; kk < KKc; ++kk) {
    const int ky = kk / 3;
    const int kx = kk % 3;
    float oy = __builtin_nontemporal_load(&ob[(2 * kk) * HWc]);
    float ox = __builtin_nontemporal_load(&ob[(2 * kk + 1) * HWc]);
    float py = oy + fh + (float)ky;
    float px = ox + fw + (float)kx;
    float y0f = floorf(py);
    float x0f = floorf(px);
    float wy = py - y0f;
    float wx = px - x0f;
    int y0 = (int)y0f;
    int x0 = (int)x0f;
    int y1 = y0 + 1;
    int x1 = x0 + 1;

    // validity folded into weights (factors exactly 0/1 -> matches reference)
    float vy0 = ((unsigned)y0 < (unsigned)Hc) ? 1.f : 0.f;
    float vy1 = ((unsigned)y1 < (unsigned)Hc) ? 1.f : 0.f;
    float vx0 = ((unsigned)x0 < (unsigned)Wc) ? 1.f : 0.f;
    float vx1 = ((unsigned)x1 < (unsigned)Wc) ? 1.f : 0.f;
    float wy0 = 1.f - wy;
    float wx0 = 1.f - wx;
    wt[kk][0] = (wy0 * wx0) * (vy0 * vx0);
    wt[kk][1] = (wy0 * wx) * (vy0 * vx1);
    wt[kk][2] = (wy * wx0) * (vy1 * vx0);
    wt[kk][3] = (wy * wx) * (vy1 * vx1);

    int y0c = min(max(y0, 0), Hc - 1);
    int y1c = min(max(y1, 0), Hc - 1);
    int x0c = min(max(x0, 0), Wc - 1);
    int x1c = min(max(x1, 0), Wc - 1);
    addr[kk][0] = (y0c << 9) + x0c;
    addr[kk][1] = (y0c << 9) + x1c;
    addr[kk][2] = (y1c << 9) + x0c;
    addr[kk][3] = (y1c << 9) + x1c;
  }

  float acc[Oc];
#pragma unroll
  for (int o = 0; o < Oc; ++o) acc[o] = bias[o];

  // phase 2: gathers (4 x dwordx4 per tap) + bilinear + einsum
#pragma unroll
  for (int kk = 0; kk < KKc; ++kk) {
    float4 v00 = xb[addr[kk][0]];
    float4 v01 = xb[addr[kk][1]];
    float4 v10 = xb[addr[kk][2]];
    float4 v11 = xb[addr[kk][3]];
    float w00 = wt[kk][0], w01 = wt[kk][1], w10 = wt[kk][2], w11 = wt[kk][3];

    float val0 = v00.x * w00 + v01.x * w01 + v10.x * w10 + v11.x * w11;
    float val1 = v00.y * w00 + v01.y * w01 + v10.y * w10 + v11.y * w11;
    float val2 = v00.z * w00 + v01.z * w01 + v10.z * w10 + v11.z * w11;

    const float* wk = weight + kk;  // compile-time indexed -> scalar K$ loads
#pragma unroll
    for (int o = 0; o < Oc; ++o) {
      acc[o] = fmaf(wk[o * 27 + 0], val0,
               fmaf(wk[o * 27 + 9], val1,
               fmaf(wk[o * 27 + 18], val2, acc[o])));
    }
  }

  float* op = out + b * (Oc * HWc) + hw;
#pragma unroll
  for (int o = 0; o < Oc; ++o)
    __builtin_nontemporal_store(acc[o], &op[o * HWc]);
}

// ---------- fallback (ws too small): original single-pass kernel ----------
__global__ __launch_bounds__(256) void dcn_fallback(
    const float* __restrict__ x,
    const float* __restrict__ offsets,
    const float* __restrict__ weight,
    const float* __restrict__ bias,
    float* __restrict__ out) {
  int pix = blockIdx.x * 256 + threadIdx.x;
  int b = pix >> 18;
  int hw = pix & (HWc - 1);
  int h = hw >> 9;
  int w = hw & 511;
  const float* xb = x + b * (Cc * HWc);
  const float* ob = offsets + b * (2 * KKc * HWc) + hw;
  float acc[Oc];
#pragma unroll
  for (int o = 0; o < Oc; ++o) acc[o] = bias[o];
  const float fh = (float)(h - 1);
  const float fw = (float)(w - 1);
#pragma unroll
  for (int kk = 0; kk < KKc; ++kk) {
    const int ky = kk / 3;
    const int kx = kk % 3;
    float oy = ob[(2 * kk) * HWc];
    float ox = ob[(2 * kk + 1) * HWc];
    float py = oy + fh + (float)ky;
    float px = ox + fw + (float)kx;
    float y0f = floorf(py), x0f = floorf(px);
    float wy = py - y0f, wx = px - x0f;
    int y0 = (int)y0f, x0 = (int)x0f, y1 = y0 + 1, x1 = x0 + 1;
    float vy0 = ((unsigned)y0 < (unsigned)Hc) ? 1.f : 0.f;
    float vy1 = ((unsigned)y1 < (unsigned)Hc) ? 1.f : 0.f;
    float vx0 = ((unsigned)x0 < (unsigned)Wc) ? 1.f : 0.f;
    float vx1 = ((unsigned)x1 < (unsigned)Wc) ? 1.f : 0.f;
    float wy0 = 1.f - wy, wx0 = 1.f - wx;
    float w00 = (wy0 * wx0) * (vy0 * vx0);
    float w01 = (wy0 * wx) * (vy0 * vx1);
    float w10 = (wy * wx0) * (vy1 * vx0);
    float w11 = (wy * wx) * (vy1 * vx1);
    int y0c = min(max(y0, 0), Hc - 1);
    int y1c = min(max(y1, 0), Hc - 1);
    int x0c = min(max(x0, 0), Wc - 1);
    int x1c = min(max(x1, 0), Wc - 1);
    int a00 = (y0c << 9) + x0c, a01 = (y0c << 9) + x1c;
    int a10 = (y1c << 9) + x0c, a11 = (y1c << 9) + x1c;
    float val[Cc];
#pragma unroll
    for (int c = 0; c < Cc; ++c) {
      const float* xc = xb + c * HWc;
      val[c] = xc[a00] * w00 + xc[a01] * w01 + xc[a10] * w10 + xc[a11] * w11;
    }
    const float* wk = weight + kk;
#pragma unroll
    for (int o = 0; o < Oc; ++o)
#pragma unroll
      for (int c = 0; c < Cc; ++c)
        acc[o] = fmaf(wk[o * 27 + c * 9], val[c], acc[o]);
  }
  float* op = out + b * (Oc * HWc) + hw;
#pragma unroll
  for (int o = 0; o < Oc; ++o) op[o * HWc] = acc[o];
}

extern "C" void kernel_launch(void* const* d_in, const int* in_sizes, int n_in,
                              void* d_out, int out_size, void* d_ws, size_t ws_size,
                              hipStream_t stream) {
  const float* x = (const float*)d_in[0];
  const float* offsets = (const float*)d_in[1];
  const float* weight = (const float*)d_in[2];
  const float* bias = (const float*)d_in[3];
  float* out = (float*)d_out;

  const int total = Bc * HWc;                        // 2,097,152 pixels
  const size_t xt_bytes = (size_t)total * 16;        // 32 MiB channels-last buffer
  dim3 grid(total / 256), block(256);

  if (ws_size >= xt_bytes) {
    float4* xt = (float4*)d_ws;
    hipLaunchKernelGGL(transpose_kernel, grid, block, 0, stream, x, xt);
    hipLaunchKernelGGL(dcn_main, grid, block, 0, stream,
                       (const float4*)xt, offsets, weight, bias, out);
  } else {
    hipLaunchKernelGGL(dcn_fallback, grid, block, 0, stream,
                       x, offsets, weight, bias, out);
  }
}